// Round 2
// baseline (4030.750 us; speedup 1.0000x reference)
//
#include <hip/hip_runtime.h>
#include <math.h>

#define HID 128
#define LSEQ 1024
#define NB 64  // batch

typedef __attribute__((ext_vector_type(4))) float f32x4;
typedef __attribute__((ext_vector_type(8))) short bf16x8;
typedef __attribute__((ext_vector_type(8))) unsigned short u16x8;
typedef __attribute__((ext_vector_type(4))) unsigned short u16x4;

__device__ __forceinline__ unsigned short f2bf(float x) {
    union { float f; unsigned int u; } a; a.f = x;
    unsigned int r = a.u + 0x7FFFu + ((a.u >> 16) & 1u);
    return (unsigned short)(r >> 16);
}
__device__ __forceinline__ float bf2f(unsigned short h) {
    union { float f; unsigned int u; } a; a.u = ((unsigned int)h) << 16;
    return a.f;
}
__device__ __forceinline__ float sigmoidf_(float x) { return 1.0f / (1.0f + __expf(-x)); }
__device__ __forceinline__ float seluf_(float x) {
    const float sc = 1.0507009873554805f, al = 1.6732632423543772f;
    return x > 0.0f ? sc * x : sc * al * (__expf(x) - 1.0f);
}

// W (K x N fp32 row-major) -> Wt (N x K bf16 row-major)
__global__ __launch_bounds__(256) void conv_wt(const float* __restrict__ W,
                                               unsigned short* __restrict__ Wt,
                                               int K, int N) {
    int idx = blockIdx.x * 256 + threadIdx.x;
    if (idx >= K * N) return;
    int k = idx / N, n = idx - k * N;
    Wt[(size_t)n * K + k] = f2bf(W[idx]);
}

// C[M x Nc] = A[M x K] * Bt[Nc x K]^T. A row-major fp32 (AF32) or bf16; Bt bf16 row-major.
// C bf16. Tile 128x128, BK=64, 256 threads = 4 waves (2x2 of 64x64), mfma 16x16x32 bf16.
// LDS tiles [128][64] bf16 with XOR swizzle (byte ^= (row&7)<<4) on both write and read.
template <bool AF32>
__global__ __launch_bounds__(256) void gemm_mfma(const void* __restrict__ Av,
                                                 const unsigned short* __restrict__ Bt,
                                                 unsigned short* __restrict__ C,
                                                 int K, int Nc) {
    __shared__ __align__(16) unsigned short lA[128 * 64];
    __shared__ __align__(16) unsigned short lB[128 * 64];

    const int tid = threadIdx.x;
    const int m0 = blockIdx.x * 128;
    const int n0 = blockIdx.y * 128;

    const int c8 = tid & 7;   // which 16B chunk of a 64-col row
    const int r0 = tid >> 3;  // 0..31

    const int lane = tid & 63;
    const int wid = tid >> 6;
    const int wr = wid >> 1, wc = wid & 1;
    const int rlo = lane & 15, g = lane >> 4;

    f32x4 acc[4][4] = {};

    for (int k0 = 0; k0 < K; k0 += 64) {
#pragma unroll
        for (int i = 0; i < 4; ++i) {
            const int r = r0 + 32 * i;
            const int dst = r * 64 + ((c8 * 8) ^ ((r & 7) * 8));
            if constexpr (AF32) {
                const float* A = (const float*)Av;
                const float4* p = (const float4*)(A + (size_t)(m0 + r) * K + k0 + c8 * 8);
                const float4 v0 = p[0], v1 = p[1];
                u16x8 w;
                w[0] = f2bf(v0.x); w[1] = f2bf(v0.y); w[2] = f2bf(v0.z); w[3] = f2bf(v0.w);
                w[4] = f2bf(v1.x); w[5] = f2bf(v1.y); w[6] = f2bf(v1.z); w[7] = f2bf(v1.w);
                *(u16x8*)(lA + dst) = w;
            } else {
                const unsigned short* A = (const unsigned short*)Av;
                *(u16x8*)(lA + dst) = *(const u16x8*)(A + (size_t)(m0 + r) * K + k0 + c8 * 8);
            }
            *(u16x8*)(lB + dst) = *(const u16x8*)(Bt + (size_t)(n0 + r) * K + k0 + c8 * 8);
        }
        __syncthreads();

        bf16x8 af[2][4], bff[2][4];
#pragma unroll
        for (int kk = 0; kk < 2; ++kk) {
            const int ke = kk * 32 + g * 8;
#pragma unroll
            for (int m = 0; m < 4; ++m) {
                const int row = wr * 64 + m * 16 + rlo;
                af[kk][m] = *(const bf16x8*)(lA + row * 64 + (ke ^ ((row & 7) * 8)));
            }
#pragma unroll
            for (int n = 0; n < 4; ++n) {
                const int row = wc * 64 + n * 16 + rlo;
                bff[kk][n] = *(const bf16x8*)(lB + row * 64 + (ke ^ ((row & 7) * 8)));
            }
        }
#pragma unroll
        for (int kk = 0; kk < 2; ++kk)
#pragma unroll
            for (int m = 0; m < 4; ++m)
#pragma unroll
                for (int n = 0; n < 4; ++n)
                    acc[m][n] = __builtin_amdgcn_mfma_f32_16x16x32_bf16(af[kk][m], bff[kk][n],
                                                                        acc[m][n], 0, 0, 0);
        __syncthreads();
    }

    // C/D layout (verified): col = lane&15, row = (lane>>4)*4 + reg
#pragma unroll
    for (int m = 0; m < 4; ++m)
#pragma unroll
        for (int n = 0; n < 4; ++n) {
            const int col = n0 + wc * 64 + n * 16 + rlo;
#pragma unroll
            for (int j = 0; j < 4; ++j) {
                const int row = m0 + wr * 64 + m * 16 + g * 4 + j;
                C[(size_t)row * Nc + col] = f2bf(acc[m][n][j]);
            }
        }
}

// One direction's scan over a time chunk. U: (T, B, H, kw) bf16 (this dir only).
// Xprev/Xout: (L, B, 256) bf16. carry: per-channel c state (fp32).
__global__ __launch_bounds__(256) void sru_scan(const unsigned short* __restrict__ U,
                                                const unsigned short* __restrict__ Xprev,
                                                const float* __restrict__ bias,
                                                float* __restrict__ carry,
                                                unsigned short* __restrict__ Xout,
                                                int kw, int dir, int T, int t0, int init) {
    const int ch = blockIdx.x * 256 + threadIdx.x;  // 0..8191
    const int b = ch >> 7, h = ch & 127;
    const float bfb = bias[dir * HID + h];
    const float brb = bias[2 * HID + dir * HID + h];
    float c = init ? 0.0f : carry[ch];

    int tl = dir ? (T - 1) : 0;
    const int st = dir ? -1 : 1;
#pragma unroll 2
    for (int s = 0; s < T; ++s, tl += st) {
        const size_t urow = ((size_t)tl * NB + b) * HID + h;
        const size_t xrow = ((size_t)(t0 + tl) * NB + b) * (2 * HID) + dir * HID + h;
        float u0, u1, u2, xp;
        if (kw == 4) {
            const u16x4 u = *(const u16x4*)(U + urow * 4);
            u0 = bf2f(u[0]); u1 = bf2f(u[1]); u2 = bf2f(u[2]); xp = bf2f(u[3]);
        } else {
            const unsigned short* up = U + urow * 3;
            u0 = bf2f(up[0]); u1 = bf2f(up[1]); u2 = bf2f(up[2]);
            xp = bf2f(Xprev[xrow]);
        }
        const float f = sigmoidf_(u1 + bfb);
        const float r = sigmoidf_(u2 + brb);
        c = f * c + (1.0f - f) * u0;
        const float ho = r * seluf_(c) + (1.0f - r) * xp;
        Xout[xrow] = f2bf(ho);
    }
    carry[ch] = c;
}

__global__ __launch_bounds__(256) void pool1(const unsigned short* __restrict__ X,
                                             float* __restrict__ part) {
    const int blk = blockIdx.x;  // b*16 + tc
    const int b = blk >> 4, tc = blk & 15;
    const int chn = threadIdx.x;
    float s = 0.0f;
    for (int i = 0; i < 64; ++i) {
        const int t = tc * 64 + i;
        s += bf2f(X[((size_t)t * NB + b) * 256 + chn]);
    }
    part[(size_t)blk * 256 + chn] = s;
}

__global__ __launch_bounds__(256) void pool2(const float* __restrict__ part,
                                             const float* __restrict__ gamma,
                                             const float* __restrict__ beta,
                                             float* __restrict__ out) {
    const int b = blockIdx.x, chn = threadIdx.x;
    float s = 0.0f;
#pragma unroll
    for (int i = 0; i < 16; ++i) s += part[(size_t)(b * 16 + i) * 256 + chn];
    const float feat = s * (1.0f / LSEQ);
    __shared__ float red[256];
    red[chn] = feat; __syncthreads();
    for (int off = 128; off > 0; off >>= 1) { if (chn < off) red[chn] += red[chn + off]; __syncthreads(); }
    const float mu = red[0] * (1.0f / 256.0f);
    __syncthreads();
    const float d = feat - mu;
    red[chn] = d * d; __syncthreads();
    for (int off = 128; off > 0; off >>= 1) { if (chn < off) red[chn] += red[chn + off]; __syncthreads(); }
    const float var = red[0] * (1.0f / 256.0f);
    out[b * 256 + chn] = d * rsqrtf(var + 1e-5f) * gamma[chn] + beta[chn];
}

extern "C" void kernel_launch(void* const* d_in, const int* in_sizes, int n_in,
                              void* d_out, int out_size, void* d_ws, size_t ws_size,
                              hipStream_t stream) {
    // dict order: input, W0, b0, gamma, beta, W1, b1, W2, b2, W3, b3
    const float* input = (const float*)d_in[0];
    const float* gamma = (const float*)d_in[3];
    const float* beta  = (const float*)d_in[4];
    const float* Wl[4] = { (const float*)d_in[1], (const float*)d_in[5],
                           (const float*)d_in[7], (const float*)d_in[9] };
    const float* bl[4] = { (const float*)d_in[2], (const float*)d_in[6],
                           (const float*)d_in[8], (const float*)d_in[10] };
    float* out = (float*)d_out;

    char* base = (char*)d_ws;
    size_t off = 0;
    auto alloc = [&](size_t bytes) { size_t o = off; off = (off + bytes + 255) & ~(size_t)255; return o; };

    unsigned short* Wt[4];
    Wt[0] = (unsigned short*)(base + alloc((size_t)1024 * 128 * 2));
    for (int i = 1; i < 4; ++i) Wt[i] = (unsigned short*)(base + alloc((size_t)768 * 256 * 2));
    unsigned short* Xa = (unsigned short*)(base + alloc((size_t)LSEQ * NB * 256 * 2));  // 33.5 MB
    unsigned short* Xb = (unsigned short*)(base + alloc((size_t)LSEQ * NB * 256 * 2));  // 33.5 MB
    float* carry = (float*)(base + alloc((size_t)2 * 8192 * 4));
    // U region; pool partials alias it (pool runs after all scans)
    if (ws_size < off + (1u << 20)) return;
    const size_t uavail = ws_size - off;
    unsigned short* U = (unsigned short*)(base + off);
    float* part = (float*)(base + off);

    int T = 0;
    for (int t = 1024; t >= 2; t >>= 1)
        if ((size_t)t * 65536 <= uavail) { T = t; break; }  // k=4 half-U chunk is the max
    if (T == 0) return;
    const int C = LSEQ / T;

    conv_wt<<<(128 * 1024 + 255) / 256, 256, 0, stream>>>(Wl[0], Wt[0], 128, 1024);
    for (int i = 1; i < 4; ++i)
        conv_wt<<<(256 * 768 + 255) / 256, 256, 0, stream>>>(Wl[i], Wt[i], 256, 768);

    const unsigned short* Xin[4] = { nullptr, Xa, Xb, Xa };
    unsigned short* Xout[4] = { Xa, Xb, Xa, Xb };

    for (int layer = 0; layer < 4; ++layer) {
        const int kw = (layer == 0) ? 4 : 3;
        const int K = (layer == 0) ? 128 : 256;
        const int Nc = HID * kw;  // 512 or 384 (one direction's columns)
        const dim3 ggrid(T * NB / 128, Nc / 128);
        for (int dir = 0; dir < 2; ++dir) {
            const unsigned short* Bts = Wt[layer] + (size_t)dir * Nc * K;
            for (int cc = 0; cc < C; ++cc) {
                const int ci = dir ? (C - 1 - cc) : cc;  // fwd ascending, bwd descending
                if (layer == 0) {
                    gemm_mfma<true><<<ggrid, 256, 0, stream>>>(
                        input + (size_t)ci * T * NB * K, Bts, U, K, Nc);
                } else {
                    gemm_mfma<false><<<ggrid, 256, 0, stream>>>(
                        Xin[layer] + (size_t)ci * T * NB * K, Bts, U, K, Nc);
                }
                sru_scan<<<32, 256, 0, stream>>>(U, Xin[layer], bl[layer],
                                                 carry + dir * 8192, Xout[layer],
                                                 kw, dir, T, ci * T, cc == 0 ? 1 : 0);
            }
        }
    }
    pool1<<<1024, 256, 0, stream>>>(Xb, part);
    pool2<<<NB, 256, 0, stream>>>(part, gamma, beta, out);
}

// Round 3
// 613.040 us; speedup vs baseline: 6.5750x; 6.5750x over previous
//
#include <hip/hip_runtime.h>
#include <math.h>

#define HID 128
#define LSEQ 1024
#define NB 64  // batch
#define CH_PER_DIR 8192  // NB * HID
#define SUB 32           // subchunk length for chunk-parallel scan

typedef __attribute__((ext_vector_type(4))) float f32x4;
typedef __attribute__((ext_vector_type(8))) short bf16x8;
typedef __attribute__((ext_vector_type(8))) unsigned short u16x8;
typedef __attribute__((ext_vector_type(4))) unsigned short u16x4;

__device__ __forceinline__ unsigned short f2bf(float x) {
    union { float f; unsigned int u; } a; a.f = x;
    unsigned int r = a.u + 0x7FFFu + ((a.u >> 16) & 1u);
    return (unsigned short)(r >> 16);
}
__device__ __forceinline__ float bf2f(unsigned short h) {
    union { float f; unsigned int u; } a; a.u = ((unsigned int)h) << 16;
    return a.f;
}
__device__ __forceinline__ float sigmoidf_(float x) { return 1.0f / (1.0f + __expf(-x)); }
__device__ __forceinline__ float seluf_(float x) {
    const float sc = 1.0507009873554805f, al = 1.6732632423543772f;
    return x > 0.0f ? sc * x : sc * al * (__expf(x) - 1.0f);
}

// W (K x N fp32 row-major) -> Wt (N x K bf16 row-major)
__global__ __launch_bounds__(256) void conv_wt(const float* __restrict__ W,
                                               unsigned short* __restrict__ Wt,
                                               int K, int N) {
    int idx = blockIdx.x * 256 + threadIdx.x;
    if (idx >= K * N) return;
    int k = idx / N, n = idx - k * N;
    Wt[(size_t)n * K + k] = f2bf(W[idx]);
}

// C[M x Nc] = A[M x K] * Bt[Nc x K]^T. 128x128 tile, BK=64, 4 waves, mfma 16x16x32 bf16.
template <bool AF32>
__global__ __launch_bounds__(256) void gemm_mfma(const void* __restrict__ Av,
                                                 const unsigned short* __restrict__ Bt,
                                                 unsigned short* __restrict__ C,
                                                 int K, int Nc) {
    __shared__ __align__(16) unsigned short lA[128 * 64];
    __shared__ __align__(16) unsigned short lB[128 * 64];

    const int tid = threadIdx.x;
    const int m0 = blockIdx.x * 128;
    const int n0 = blockIdx.y * 128;

    const int c8 = tid & 7;
    const int r0 = tid >> 3;

    const int lane = tid & 63;
    const int wid = tid >> 6;
    const int wr = wid >> 1, wc = wid & 1;
    const int rlo = lane & 15, g = lane >> 4;

    f32x4 acc[4][4] = {};

    for (int k0 = 0; k0 < K; k0 += 64) {
#pragma unroll
        for (int i = 0; i < 4; ++i) {
            const int r = r0 + 32 * i;
            const int dst = r * 64 + ((c8 * 8) ^ ((r & 7) * 8));
            if constexpr (AF32) {
                const float* A = (const float*)Av;
                const float4* p = (const float4*)(A + (size_t)(m0 + r) * K + k0 + c8 * 8);
                const float4 v0 = p[0], v1 = p[1];
                u16x8 w;
                w[0] = f2bf(v0.x); w[1] = f2bf(v0.y); w[2] = f2bf(v0.z); w[3] = f2bf(v0.w);
                w[4] = f2bf(v1.x); w[5] = f2bf(v1.y); w[6] = f2bf(v1.z); w[7] = f2bf(v1.w);
                *(u16x8*)(lA + dst) = w;
            } else {
                const unsigned short* A = (const unsigned short*)Av;
                *(u16x8*)(lA + dst) = *(const u16x8*)(A + (size_t)(m0 + r) * K + k0 + c8 * 8);
            }
            *(u16x8*)(lB + dst) = *(const u16x8*)(Bt + (size_t)(n0 + r) * K + k0 + c8 * 8);
        }
        __syncthreads();

        bf16x8 af[2][4], bff[2][4];
#pragma unroll
        for (int kk = 0; kk < 2; ++kk) {
            const int ke = kk * 32 + g * 8;
#pragma unroll
            for (int m = 0; m < 4; ++m) {
                const int row = wr * 64 + m * 16 + rlo;
                af[kk][m] = *(const bf16x8*)(lA + row * 64 + (ke ^ ((row & 7) * 8)));
            }
#pragma unroll
            for (int n = 0; n < 4; ++n) {
                const int row = wc * 64 + n * 16 + rlo;
                bff[kk][n] = *(const bf16x8*)(lB + row * 64 + (ke ^ ((row & 7) * 8)));
            }
        }
#pragma unroll
        for (int kk = 0; kk < 2; ++kk)
#pragma unroll
            for (int m = 0; m < 4; ++m)
#pragma unroll
                for (int n = 0; n < 4; ++n)
                    acc[m][n] = __builtin_amdgcn_mfma_f32_16x16x32_bf16(af[kk][m], bff[kk][n],
                                                                        acc[m][n], 0, 0, 0);
        __syncthreads();
    }

#pragma unroll
    for (int m = 0; m < 4; ++m)
#pragma unroll
        for (int n = 0; n < 4; ++n) {
            const int col = n0 + wc * 64 + n * 16 + rlo;
#pragma unroll
            for (int j = 0; j < 4; ++j) {
                const int row = m0 + wr * 64 + m * 16 + g * 4 + j;
                C[(size_t)row * Nc + col] = f2bf(acc[m][n][j]);
            }
        }
}

// ---- chunk-parallel SRU scan (3 phases) ----
// U: (T, B, H, KW) bf16, one direction. Channels ch = b*128+h (8192).
// Logical step s runs 0..T-1; physical t = dir ? T-1-s : s.

// Phase A: per (ch, subchunk q): a = prod f, b = c scanned from 0.
template <int KW>
__global__ __launch_bounds__(256) void scanA(const unsigned short* __restrict__ U,
                                             const float* __restrict__ bias,
                                             float* __restrict__ aArr,
                                             float* __restrict__ bArr,
                                             int dir, int T) {
    const int gid = blockIdx.x * 256 + threadIdx.x;
    const int ch = gid & (CH_PER_DIR - 1);
    const int q = gid >> 13;
    const int b = ch >> 7, h = ch & 127;
    const float bfb = bias[dir * HID + h];

    float aa = 1.0f, cc = 0.0f;
#pragma unroll 4
    for (int i = 0; i < SUB; ++i) {
        const int s = q * SUB + i;
        const int t = dir ? (T - 1 - s) : s;
        const size_t urow = ((size_t)t * NB + b) * HID + h;
        const float u0 = bf2f(U[urow * KW + 0]);
        const float u1 = bf2f(U[urow * KW + 1]);
        const float f = sigmoidf_(u1 + bfb);
        cc = f * cc + (1.0f - f) * u0;
        aa *= f;
    }
    aArr[(size_t)q * CH_PER_DIR + ch] = aa;
    bArr[(size_t)q * CH_PER_DIR + ch] = cc;
}

// Phase B: per channel, exclusive scan over Q subchunk summaries.
__global__ __launch_bounds__(256) void scanB(const float* __restrict__ aArr,
                                             const float* __restrict__ bArr,
                                             float* __restrict__ cin,
                                             float* __restrict__ carry,
                                             int Q, int init) {
    const int ch = blockIdx.x * 256 + threadIdx.x;  // 0..8191
    float c = init ? 0.0f : carry[ch];
    for (int q = 0; q < Q; ++q) {
        cin[(size_t)q * CH_PER_DIR + ch] = c;
        c = aArr[(size_t)q * CH_PER_DIR + ch] * c + bArr[(size_t)q * CH_PER_DIR + ch];
    }
    carry[ch] = c;
}

// Phase C: per (ch, q): redo scan from exact cin, produce h outputs.
template <int KW, bool XP_FROM_U>
__global__ __launch_bounds__(256) void scanC(const unsigned short* __restrict__ U,
                                             const unsigned short* __restrict__ Xprev,
                                             const float* __restrict__ bias,
                                             const float* __restrict__ cin,
                                             unsigned short* __restrict__ Xout,
                                             int dir, int T, int t0) {
    const int gid = blockIdx.x * 256 + threadIdx.x;
    const int ch = gid & (CH_PER_DIR - 1);
    const int q = gid >> 13;
    const int b = ch >> 7, h = ch & 127;
    const float bfb = bias[dir * HID + h];
    const float brb = bias[2 * HID + dir * HID + h];

    float c = cin[(size_t)q * CH_PER_DIR + ch];
#pragma unroll 4
    for (int i = 0; i < SUB; ++i) {
        const int s = q * SUB + i;
        const int t = dir ? (T - 1 - s) : s;
        const size_t urow = ((size_t)t * NB + b) * HID + h;
        const size_t xrow = ((size_t)(t0 + t) * NB + b) * (2 * HID) + dir * HID + h;
        float u0, u1, u2, xp;
        if constexpr (XP_FROM_U) {
            const u16x4 u = *(const u16x4*)(U + urow * 4);
            u0 = bf2f(u[0]); u1 = bf2f(u[1]); u2 = bf2f(u[2]); xp = bf2f(u[3]);
        } else {
            const unsigned short* up = U + urow * KW;
            u0 = bf2f(up[0]); u1 = bf2f(up[1]); u2 = bf2f(up[2]);
            xp = bf2f(Xprev[xrow]);
        }
        const float f = sigmoidf_(u1 + bfb);
        const float r = sigmoidf_(u2 + brb);
        c = f * c + (1.0f - f) * u0;
        const float ho = r * seluf_(c) + (1.0f - r) * xp;
        Xout[xrow] = f2bf(ho);
    }
}

__global__ __launch_bounds__(256) void pool1(const unsigned short* __restrict__ X,
                                             float* __restrict__ part) {
    const int blk = blockIdx.x;  // b*16 + tc
    const int b = blk >> 4, tc = blk & 15;
    const int chn = threadIdx.x;
    float s = 0.0f;
    for (int i = 0; i < 64; ++i) {
        const int t = tc * 64 + i;
        s += bf2f(X[((size_t)t * NB + b) * 256 + chn]);
    }
    part[(size_t)blk * 256 + chn] = s;
}

__global__ __launch_bounds__(256) void pool2(const float* __restrict__ part,
                                             const float* __restrict__ gamma,
                                             const float* __restrict__ beta,
                                             float* __restrict__ out) {
    const int b = blockIdx.x, chn = threadIdx.x;
    float s = 0.0f;
#pragma unroll
    for (int i = 0; i < 16; ++i) s += part[(size_t)(b * 16 + i) * 256 + chn];
    const float feat = s * (1.0f / LSEQ);
    __shared__ float red[256];
    red[chn] = feat; __syncthreads();
    for (int off = 128; off > 0; off >>= 1) { if (chn < off) red[chn] += red[chn + off]; __syncthreads(); }
    const float mu = red[0] * (1.0f / 256.0f);
    __syncthreads();
    const float d = feat - mu;
    red[chn] = d * d; __syncthreads();
    for (int off = 128; off > 0; off >>= 1) { if (chn < off) red[chn] += red[chn + off]; __syncthreads(); }
    const float var = red[0] * (1.0f / 256.0f);
    out[b * 256 + chn] = d * rsqrtf(var + 1e-5f) * gamma[chn] + beta[chn];
}

extern "C" void kernel_launch(void* const* d_in, const int* in_sizes, int n_in,
                              void* d_out, int out_size, void* d_ws, size_t ws_size,
                              hipStream_t stream) {
    const float* input = (const float*)d_in[0];
    const float* gamma = (const float*)d_in[3];
    const float* beta  = (const float*)d_in[4];
    const float* Wl[4] = { (const float*)d_in[1], (const float*)d_in[5],
                           (const float*)d_in[7], (const float*)d_in[9] };
    const float* bl[4] = { (const float*)d_in[2], (const float*)d_in[6],
                           (const float*)d_in[8], (const float*)d_in[10] };
    float* out = (float*)d_out;

    char* base = (char*)d_ws;
    size_t off = 0;
    auto alloc = [&](size_t bytes) { size_t o = off; off = (off + bytes + 255) & ~(size_t)255; return o; };

    unsigned short* Wt[4];
    Wt[0] = (unsigned short*)(base + alloc((size_t)1024 * 128 * 2));
    for (int i = 1; i < 4; ++i) Wt[i] = (unsigned short*)(base + alloc((size_t)768 * 256 * 2));
    unsigned short* Xa = (unsigned short*)(base + alloc((size_t)LSEQ * NB * 256 * 2));
    unsigned short* Xb = (unsigned short*)(base + alloc((size_t)LSEQ * NB * 256 * 2));
    float* carry = (float*)(base + alloc((size_t)2 * CH_PER_DIR * 4));
    float* aArr  = (float*)(base + alloc((size_t)32 * CH_PER_DIR * 4));  // Q<=32
    float* bArr  = (float*)(base + alloc((size_t)32 * CH_PER_DIR * 4));
    float* cinArr= (float*)(base + alloc((size_t)32 * CH_PER_DIR * 4));
    if (ws_size < off + (1u << 21)) return;
    const size_t uavail = ws_size - off;
    unsigned short* U = (unsigned short*)(base + off);
    float* part = (float*)(base + off);

    int T = 0;
    for (int t = 1024; t >= SUB; t >>= 1)
        if ((size_t)t * 65536 <= uavail) { T = t; break; }  // kw=4 half-U chunk bytes
    if (T == 0) return;
    const int C = LSEQ / T;
    const int Q = T / SUB;

    conv_wt<<<(128 * 1024 + 255) / 256, 256, 0, stream>>>(Wl[0], Wt[0], 128, 1024);
    for (int i = 1; i < 4; ++i)
        conv_wt<<<(256 * 768 + 255) / 256, 256, 0, stream>>>(Wl[i], Wt[i], 256, 768);

    const unsigned short* Xin[4] = { nullptr, Xa, Xb, Xa };
    unsigned short* Xout[4] = { Xa, Xb, Xa, Xb };

    const dim3 sgrid(CH_PER_DIR * Q / 256);

    for (int layer = 0; layer < 4; ++layer) {
        const int kw = (layer == 0) ? 4 : 3;
        const int K = (layer == 0) ? 128 : 256;
        const int Nc = HID * kw;  // 512 or 384
        const dim3 ggrid(T * NB / 128, Nc / 128);
        for (int dir = 0; dir < 2; ++dir) {
            const unsigned short* Bts = Wt[layer] + (size_t)dir * Nc * K;
            float* cr = carry + dir * CH_PER_DIR;
            for (int cc = 0; cc < C; ++cc) {
                const int ci = dir ? (C - 1 - cc) : cc;
                if (layer == 0) {
                    gemm_mfma<true><<<ggrid, 256, 0, stream>>>(
                        input + (size_t)ci * T * NB * K, Bts, U, K, Nc);
                } else {
                    gemm_mfma<false><<<ggrid, 256, 0, stream>>>(
                        Xin[layer] + (size_t)ci * T * NB * K, Bts, U, K, Nc);
                }
                if (kw == 4) scanA<4><<<sgrid, 256, 0, stream>>>(U, bl[layer], aArr, bArr, dir, T);
                else         scanA<3><<<sgrid, 256, 0, stream>>>(U, bl[layer], aArr, bArr, dir, T);
                scanB<<<CH_PER_DIR / 256, 256, 0, stream>>>(aArr, bArr, cinArr, cr, Q, cc == 0 ? 1 : 0);
                if (kw == 4)
                    scanC<4, true><<<sgrid, 256, 0, stream>>>(U, nullptr, bl[layer], cinArr,
                                                              Xout[layer], dir, T, ci * T);
                else
                    scanC<3, false><<<sgrid, 256, 0, stream>>>(U, Xin[layer], bl[layer], cinArr,
                                                               Xout[layer], dir, T, ci * T);
            }
        }
    }
    pool1<<<1024, 256, 0, stream>>>(Xb, part);
    pool2<<<NB, 256, 0, stream>>>(part, gamma, beta, out);
}